// Round 1
// baseline (1321.182 us; speedup 1.0000x reference)
//
#include <hip/hip_runtime.h>
#include <hip/hip_bf16.h>
#include <stdint.h>

#define DIM   2048
#define NEXP  16
#define TOPK  2
#define NTOK  2048
#define NSLOT (NTOK*TOPK)   // 4096

typedef __bf16 bf16_t;
typedef __attribute__((ext_vector_type(4))) __bf16 bf16x4;
typedef __attribute__((ext_vector_type(8))) __bf16 bf16x8;
typedef __attribute__((ext_vector_type(4))) float f32x4;

// ---------------- workspace layout (bytes) ----------------
#define WS_COUNTS    0        // int[16]
#define WS_CURSOR    64       // int[16]
#define WS_IMP       128      // float[16]
#define WS_OFFS      192      // int[17]
#define WS_TOK_TOP   4096     // int[4096]  expert id per (token,k)
#define WS_TOK_GATE  20480    // float[4096] gate weight per (token,k)
#define WS_SLOT_TOK  36864    // int[4096]  token id per compacted slot
#define WS_SLOT_GATE 53248    // float[4096]
#define WS_XBF       131072   // bf16[NTOK*DIM]   8 MB
#define WS_H         (WS_XBF + NTOK*DIM*2)  // bf16[NSLOT*DIM] 16 MB
// total ~24.2 MB

// ---------------- x -> bf16 ----------------
__global__ __launch_bounds__(256) void k_convert_x(const float* __restrict__ x,
                                                   bf16_t* __restrict__ xb) {
    int i = (blockIdx.x * 256 + threadIdx.x) * 4;
    float4 v = *reinterpret_cast<const float4*>(x + i);
    bf16x4 o;
    o[0] = (bf16_t)v.x; o[1] = (bf16_t)v.y; o[2] = (bf16_t)v.z; o[3] = (bf16_t)v.w;
    *reinterpret_cast<bf16x4*>(xb + i) = o;
}

// ---------------- gating: scores, softmax-imp, top-2, counts ----------------
__global__ __launch_bounds__(256) void k_gate(const float* __restrict__ x,
                                              const float* __restrict__ Wg,
                                              const float* __restrict__ bg,
                                              int* __restrict__ counts,
                                              float* __restrict__ imp,
                                              int* __restrict__ tok_top,
                                              float* __restrict__ tok_gate) {
    const int b = blockIdx.x;
    const int t = threadIdx.x;
    float acc[NEXP];
#pragma unroll
    for (int e = 0; e < NEXP; e++) acc[e] = 0.f;
    const float* xr = x + (size_t)b * DIM;
    for (int d = t; d < DIM; d += 256) {
        float xv = xr[d];
        const float* wr = Wg + (size_t)d * NEXP;
#pragma unroll
        for (int e = 0; e < NEXP; e++) acc[e] += xv * wr[e];
    }
#pragma unroll
    for (int e = 0; e < NEXP; e++) {
        for (int off = 32; off > 0; off >>= 1) acc[e] += __shfl_down(acc[e], off, 64);
    }
    __shared__ float red[4][NEXP];
    __shared__ float sc[NEXP];
    const int wv = t >> 6, lane = t & 63;
    if (lane == 0) {
#pragma unroll
        for (int e = 0; e < NEXP; e++) red[wv][e] = acc[e];
    }
    __syncthreads();
    if (t < NEXP) sc[t] = red[0][t] + red[1][t] + red[2][t] + red[3][t] + bg[t];
    __syncthreads();
    if (t == 0) {
        float mx = sc[0];
#pragma unroll
        for (int e = 1; e < NEXP; e++) mx = fmaxf(mx, sc[e]);
        float p[NEXP], sum = 0.f;
#pragma unroll
        for (int e = 0; e < NEXP; e++) { p[e] = expf(sc[e] - mx); sum += p[e]; }
        float inv = 1.f / sum;
#pragma unroll
        for (int e = 0; e < NEXP; e++) atomicAdd(&imp[e], p[e] * inv);
        // top-2 (ties -> lower index, matching lax.top_k)
        int i0 = 0;
#pragma unroll
        for (int e = 1; e < NEXP; e++) if (sc[e] > sc[i0]) i0 = e;
        int i1 = -1;
#pragma unroll
        for (int e = 0; e < NEXP; e++)
            if (e != i0 && (i1 < 0 || sc[e] > sc[i1])) i1 = e;
        float g0 = 1.f / (1.f + expf(sc[i1] - sc[i0]));  // softmax over {s0,s1}
        float g1 = 1.f - g0;
        tok_top[b * 2 + 0] = i0; tok_top[b * 2 + 1] = i1;
        tok_gate[b * 2 + 0] = g0; tok_gate[b * 2 + 1] = g1;
        atomicAdd(&counts[i0], 1);
        atomicAdd(&counts[i1], 1);
    }
}

// ---------------- offsets + aux losses ----------------
__global__ void k_offsets(const int* __restrict__ counts, const float* __restrict__ imp,
                          int* __restrict__ offs, int* __restrict__ cursor,
                          float* __restrict__ losses) {
    if (threadIdx.x == 0) {
        int o = 0;
        for (int e = 0; e < NEXP; e++) { offs[e] = o; o += counts[e]; }
        offs[NEXP] = o;
        // load_loss = var(counts, ddof=1) / (E*(B/E)) = var / 2048
        float m = (float)o / NEXP;
        float v = 0.f;
        for (int e = 0; e < NEXP; e++) { float d = (float)counts[e] - m; v += d * d; }
        v /= (NEXP - 1);
        losses[0] = v / (float)NTOK;
        // importance_loss = var(imp, ddof=1) / (mean(imp)+1e-8)
        float ms = 0.f;
        for (int e = 0; e < NEXP; e++) ms += imp[e];
        ms /= NEXP;
        float vv = 0.f;
        for (int e = 0; e < NEXP; e++) { float d = imp[e] - ms; vv += d * d; }
        vv /= (NEXP - 1);
        losses[1] = vv / (ms + 1e-8f);
    }
    if (threadIdx.x < NEXP) cursor[threadIdx.x] = 0;
}

// ---------------- compaction: (token,k) -> per-expert slots ----------------
__global__ __launch_bounds__(256) void k_scatter(const int* __restrict__ tok_top,
                                                 const float* __restrict__ tok_gate,
                                                 const int* __restrict__ offs,
                                                 int* __restrict__ cursor,
                                                 int* __restrict__ slot_tok,
                                                 float* __restrict__ slot_gate) {
    int i = blockIdx.x * 256 + threadIdx.x;  // 0..4095
    int e = tok_top[i];
    int pos = atomicAdd(&cursor[e], 1);
    int slot = offs[e] + pos;
    slot_tok[slot] = i >> 1;
    slot_gate[slot] = tok_gate[i];
}

// ---------------- grouped GEMM ----------------
// PHASE 1: H[slot] = relu(Xbf[token(slot)] @ W1_e + b1_e)   (bf16 out)
// PHASE 2: out[token] += gate * (H[slot] @ W2_e + b2_e)     (f32 atomics)
#define BM 256
#define BN 128
#define BK 32
#define APITCH 32   // bf16 elems per A row (no pad: 64B rows, even superbank spread)
#define BPITCH 40   // bf16 elems per B row (80B rows: 5n+q covers all 8 superbanks)

template <int PHASE>
__global__ __launch_bounds__(512) void k_gemm(const float* __restrict__ Wall,
                                              const float* __restrict__ bias,
                                              const bf16_t* __restrict__ Asrc,
                                              const int* __restrict__ counts,
                                              const int* __restrict__ offs,
                                              const int* __restrict__ slot_tok,
                                              const float* __restrict__ slot_gate,
                                              bf16_t* __restrict__ Hout,
                                              float* __restrict__ out) {
    const int e  = blockIdx.z;
    const int n0 = blockIdx.x * BN;
    const int m0 = blockIdx.y * BM;
    const int cnt = counts[e];
    if (m0 >= cnt) return;
    const int off = offs[e];

    __shared__ bf16_t As[BM * APITCH];   // 16 KB  [m][k]
    __shared__ bf16_t Bs[BN * BPITCH];   // 10 KB  [n][k] (transposed, padded)

    const int t = threadIdx.x;
    const int lane = t & 63, wv = t >> 6;        // 8 waves
    const int wm = wv & 3, wn = wv >> 2;         // 4 (M) x 2 (N) wave grid
    const int l15 = lane & 15, q = lane >> 4;

    // A staging: wave wv stages rows [wv*32, wv*32+32), 2 global_load_lds(16B) per thread
    const bf16_t* arow[2];
#pragma unroll
    for (int i = 0; i < 2; i++) {
        int rl = wv * 32 + i * 16 + (lane >> 2);     // local tile row
        int slot = off + m0 + rl;
        slot = slot < (NSLOT - 1) ? slot : (NSLOT - 1);   // clamp (rows >= cnt are dummies)
        int srow = (PHASE == 1) ? slot_tok[slot] : slot;
        arow[i] = Asrc + (size_t)srow * DIM + (lane & 3) * 8;  // 16B chunk within 64B row
    }
    // B staging: thread t handles col n=t&127, k-octet kh=t>>7
    const int bn = t & 127, kh = t >> 7;
    const float* bsrc = Wall + (size_t)e * DIM * DIM + (size_t)(kh * 8) * DIM + n0 + bn;
    bf16_t* bdst = &Bs[bn * BPITCH + kh * 8];

    f32x4 acc[4][4] = {};

    for (int k0 = 0; k0 < DIM; k0 += BK) {
        __syncthreads();
        // A -> LDS (direct-to-LDS, already bf16)
#pragma unroll
        for (int i = 0; i < 2; i++) {
            bf16_t* ldst = &As[(wv * 32 + i * 16) * APITCH];  // wave-uniform base
            __builtin_amdgcn_global_load_lds(
                (const __attribute__((address_space(1))) uint32_t*)(arow[i] + k0),
                (__attribute__((address_space(3))) uint32_t*)ldst, 16, 0, 0);
        }
        // B -> LDS: 8 coalesced f32 loads down K, cvt, one 16B LDS write
        {
            const float* bs = bsrc + (size_t)k0 * DIM;
            float v[8];
#pragma unroll
            for (int kk = 0; kk < 8; kk++) v[kk] = bs[(size_t)kk * DIM];
            bf16x8 pk;
#pragma unroll
            for (int kk = 0; kk < 8; kk++) pk[kk] = (bf16_t)v[kk];
            *reinterpret_cast<bf16x8*>(bdst) = pk;  // ds_write_b128, conflict-even
        }
        __syncthreads();

        bf16x8 af[4], bfr[4];
#pragma unroll
        for (int mf = 0; mf < 4; mf++)
            af[mf] = *reinterpret_cast<const bf16x8*>(&As[(wm * 64 + mf * 16 + l15) * APITCH + q * 8]);
#pragma unroll
        for (int nf = 0; nf < 4; nf++)
            bfr[nf] = *reinterpret_cast<const bf16x8*>(&Bs[(wn * 64 + nf * 16 + l15) * BPITCH + q * 8]);
#pragma unroll
        for (int mf = 0; mf < 4; mf++)
#pragma unroll
            for (int nf = 0; nf < 4; nf++)
                acc[mf][nf] = __builtin_amdgcn_mfma_f32_16x16x32_bf16(af[mf], bfr[nf], acc[mf][nf], 0, 0, 0);
    }

    // epilogue; C/D layout: col = l15, row = q*4 + reg (m89-verified)
    const int rows_here = cnt - m0;
#pragma unroll
    for (int mf = 0; mf < 4; mf++) {
#pragma unroll
        for (int r = 0; r < 4; r++) {
            int rl = wm * 64 + mf * 16 + q * 4 + r;
            if (rl >= rows_here) continue;
            int slot = off + m0 + rl;
            if (PHASE == 1) {
#pragma unroll
                for (int nf = 0; nf < 4; nf++) {
                    int col = n0 + wn * 64 + nf * 16 + l15;
                    float h = acc[mf][nf][r] + bias[e * DIM + col];
                    h = fmaxf(h, 0.f);
                    Hout[(size_t)slot * DIM + col] = (bf16_t)h;
                }
            } else {
                float g = slot_gate[slot];
                int tok = slot_tok[slot];
#pragma unroll
                for (int nf = 0; nf < 4; nf++) {
                    int col = n0 + wn * 64 + nf * 16 + l15;
                    float y = acc[mf][nf][r] + bias[e * DIM + col];
                    atomicAdd(&out[(size_t)tok * DIM + col], g * y);
                }
            }
        }
    }
}

// ---------------- launcher ----------------
extern "C" void kernel_launch(void* const* d_in, const int* in_sizes, int n_in,
                              void* d_out, int out_size, void* d_ws, size_t ws_size,
                              hipStream_t stream) {
    const float* x  = (const float*)d_in[0];
    const float* W1 = (const float*)d_in[1];
    const float* b1 = (const float*)d_in[2];
    const float* W2 = (const float*)d_in[3];
    const float* b2 = (const float*)d_in[4];
    const float* Wg = (const float*)d_in[5];
    const float* bg = (const float*)d_in[6];
    float* out = (float*)d_out;
    char*  ws  = (char*)d_ws;

    int*    counts    = (int*)(ws + WS_COUNTS);
    int*    cursor    = (int*)(ws + WS_CURSOR);
    float*  imp       = (float*)(ws + WS_IMP);
    int*    offs      = (int*)(ws + WS_OFFS);
    int*    tok_top   = (int*)(ws + WS_TOK_TOP);
    float*  tok_gate  = (float*)(ws + WS_TOK_GATE);
    int*    slot_tok  = (int*)(ws + WS_SLOT_TOK);
    float*  slot_gate = (float*)(ws + WS_SLOT_GATE);
    bf16_t* xbf       = (bf16_t*)(ws + WS_XBF);
    bf16_t* H         = (bf16_t*)(ws + WS_H);

    hipMemsetAsync(ws, 0, 256, stream);                                   // counters
    hipMemsetAsync(out, 0, (size_t)NTOK * DIM * sizeof(float), stream);   // out accum

    k_convert_x<<<NTOK * DIM / 1024, 256, 0, stream>>>(x, xbf);
    k_gate<<<NTOK, 256, 0, stream>>>(x, Wg, bg, counts, imp, tok_top, tok_gate);
    k_offsets<<<1, 64, 0, stream>>>(counts, imp, offs, cursor, out + (size_t)NTOK * DIM);
    k_scatter<<<NSLOT / 256, 256, 0, stream>>>(tok_top, tok_gate, offs, cursor, slot_tok, slot_gate);

    dim3 grid(DIM / BN, NTOK / BM, NEXP);  // 16 x 8 x 16; dead chunks exit early
    k_gemm<1><<<grid, 512, 0, stream>>>(W1, b1, xbf, counts, offs, slot_tok, slot_gate, H, nullptr);
    k_gemm<2><<<grid, 512, 0, stream>>>(W2, b2, H, counts, offs, slot_tok, slot_gate, nullptr, out);
}

// Round 2
// 932.826 us; speedup vs baseline: 1.4163x; 1.4163x over previous
//
#include <hip/hip_runtime.h>
#include <hip/hip_bf16.h>
#include <stdint.h>

#define DIM   2048
#define NEXP  16
#define TOPK  2
#define NTOK  2048
#define NSLOT (NTOK*TOPK)   // 4096

typedef __bf16 bf16_t;
typedef __attribute__((ext_vector_type(4))) __bf16 bf16x4;
typedef __attribute__((ext_vector_type(8))) __bf16 bf16x8;
typedef __attribute__((ext_vector_type(4))) float f32x4;

// ---------------- workspace layout (bytes) ----------------
#define WS_CURSOR    0        // int[16*16]  padded: one cursor per 64B line (zeroed)
#define WS_COUNTS    1024     // int[16]     written by k_finalize
#define WS_OFFS      1152     // int[17]     written by k_finalize
#define WS_TOK_TOP   4096     // int[4096]   expert id per (token,k)
#define WS_TOK_GATE  20480    // float[4096] gate weight per (token,k)
#define WS_SLOT_TOK  36864    // int[4096]   token id per compacted slot
#define WS_SLOT_GATE 53248    // float[4096]
#define WS_IMPP      69632    // float[2048*16] per-token softmax probs (128 KB)
#define WS_XBF       262144   // bf16[NTOK*DIM]   8 MB
#define WS_H         (WS_XBF + NTOK*DIM*2)  // bf16[NSLOT*DIM] 16 MB
// total ~24.3 MB

// ---------------- x -> bf16 ----------------
__global__ __launch_bounds__(256) void k_convert_x(const float* __restrict__ x,
                                                   bf16_t* __restrict__ xb) {
    int i = (blockIdx.x * 256 + threadIdx.x) * 4;
    float4 v = *reinterpret_cast<const float4*>(x + i);
    bf16x4 o;
    o[0] = (bf16_t)v.x; o[1] = (bf16_t)v.y; o[2] = (bf16_t)v.z; o[3] = (bf16_t)v.w;
    *reinterpret_cast<bf16x4*>(xb + i) = o;
}

// ---------------- gating: one wave per token, NO global atomics ----------------
__global__ __launch_bounds__(256) void k_gate(const float* __restrict__ x,
                                              const float* __restrict__ Wg,
                                              const float* __restrict__ bg,
                                              float* __restrict__ imp_partial,
                                              int* __restrict__ tok_top,
                                              float* __restrict__ tok_gate) {
    const int tok  = blockIdx.x * 4 + (threadIdx.x >> 6);
    const int lane = threadIdx.x & 63;
    const float* xr = x + (size_t)tok * DIM;

    float acc[NEXP];
#pragma unroll
    for (int e = 0; e < NEXP; e++) acc[e] = 0.f;

#pragma unroll
    for (int i = 0; i < 8; i++) {
        int d = (i * 64 + lane) * 4;                       // 4 consecutive rows of Wg
        float4 xv = *reinterpret_cast<const float4*>(xr + d);
        const float4* wr = reinterpret_cast<const float4*>(Wg + (size_t)d * NEXP);
#pragma unroll
        for (int c = 0; c < 4; c++) {
            float xc = (&xv.x)[c];
#pragma unroll
            for (int j = 0; j < 4; j++) {
                float4 w = wr[c * 4 + j];
                acc[j * 4 + 0] += xc * w.x;
                acc[j * 4 + 1] += xc * w.y;
                acc[j * 4 + 2] += xc * w.z;
                acc[j * 4 + 3] += xc * w.w;
            }
        }
    }
    // butterfly reduce across the wave (all lanes end with full sums)
#pragma unroll
    for (int e = 0; e < NEXP; e++) {
#pragma unroll
        for (int off = 32; off > 0; off >>= 1) acc[e] += __shfl_xor(acc[e], off, 64);
    }

    if (lane == 0) {
        float sc[NEXP];
#pragma unroll
        for (int e = 0; e < NEXP; e++) sc[e] = acc[e] + bg[e];
        float mx = sc[0];
#pragma unroll
        for (int e = 1; e < NEXP; e++) mx = fmaxf(mx, sc[e]);
        float p[NEXP], sum = 0.f;
#pragma unroll
        for (int e = 0; e < NEXP; e++) { p[e] = expf(sc[e] - mx); sum += p[e]; }
        float inv = 1.f / sum;
#pragma unroll
        for (int e = 0; e < NEXP; e++) imp_partial[tok * NEXP + e] = p[e] * inv;
        // top-2 (ties -> lower index, matching lax.top_k)
        int i0 = 0;
#pragma unroll
        for (int e = 1; e < NEXP; e++) if (sc[e] > sc[i0]) i0 = e;
        int i1 = -1;
#pragma unroll
        for (int e = 0; e < NEXP; e++)
            if (e != i0 && (i1 < 0 || sc[e] > sc[i1])) i1 = e;
        float g0 = 1.f / (1.f + expf(sc[i1] - sc[i0]));  // softmax over {s0,s1}
        tok_top[tok * 2 + 0] = i0; tok_top[tok * 2 + 1] = i1;
        tok_gate[tok * 2 + 0] = g0; tok_gate[tok * 2 + 1] = 1.f - g0;
    }
}

// ---------------- finalize: counts histogram + offsets + aux losses ----------------
__global__ __launch_bounds__(256) void k_finalize(const float* __restrict__ imp_partial,
                                                  const int* __restrict__ tok_top,
                                                  int* __restrict__ counts,
                                                  int* __restrict__ offs,
                                                  float* __restrict__ losses) {
    __shared__ int   scnt[NEXP];
    __shared__ float ired[16][NEXP + 1];
    const int t = threadIdx.x;
    if (t < NEXP) scnt[t] = 0;
    __syncthreads();
    for (int i = t; i < NSLOT; i += 256) atomicAdd(&scnt[tok_top[i]], 1);
    // imp column sums: thread t handles expert (t&15), row-chunk (t>>4) of 128 rows
    {
        const int e = t & 15, ch = t >> 4;
        float s = 0.f;
        for (int r = ch * 128; r < ch * 128 + 128; r++) s += imp_partial[r * NEXP + e];
        ired[ch][e] = s;
    }
    __syncthreads();
    if (t == 0) {
        int o = 0;
        float cntf[NEXP];
        for (int e = 0; e < NEXP; e++) {
            counts[e] = scnt[e]; offs[e] = o; o += scnt[e]; cntf[e] = (float)scnt[e];
        }
        offs[NEXP] = o;
        // load_loss = var(counts, ddof=1) / (E*(B/E))
        float m = (float)o / NEXP, v = 0.f;
        for (int e = 0; e < NEXP; e++) { float d = cntf[e] - m; v += d * d; }
        losses[0] = (v / (NEXP - 1)) / (float)NTOK;
        // importance_loss = var(imp, ddof=1) / (mean(imp)+1e-8)
        float imp[NEXP];
        for (int e = 0; e < NEXP; e++) {
            float s = 0.f;
            for (int ch = 0; ch < 16; ch++) s += ired[ch][e];
            imp[e] = s;
        }
        float ms = 0.f;
        for (int e = 0; e < NEXP; e++) ms += imp[e];
        ms /= NEXP;
        float vv = 0.f;
        for (int e = 0; e < NEXP; e++) { float d = imp[e] - ms; vv += d * d; }
        losses[1] = (vv / (NEXP - 1)) / (ms + 1e-8f);
    }
}

// ---------------- compaction: padded cursors (one per 64B line) ----------------
__global__ __launch_bounds__(256) void k_scatter(const int* __restrict__ tok_top,
                                                 const float* __restrict__ tok_gate,
                                                 const int* __restrict__ offs,
                                                 int* __restrict__ cursor,
                                                 int* __restrict__ slot_tok,
                                                 float* __restrict__ slot_gate) {
    int i = blockIdx.x * 256 + threadIdx.x;  // 0..4095
    int e = tok_top[i];
    int pos = atomicAdd(&cursor[e * 16], 1);
    int slot = offs[e] + pos;
    slot_tok[slot] = i >> 1;
    slot_gate[slot] = tok_gate[i];
}

// ---------------- grouped GEMM ----------------
// PHASE 1: H[slot] = relu(Xbf[token(slot)] @ W1_e + b1_e)   (bf16 out)
// PHASE 2: out[token] += gate * (H[slot] @ W2_e + b2_e)     (f32 atomics)
#define BM 256
#define BN 128
#define BK 32
#define APITCH 32   // bf16 elems per A row
#define BPITCH 40   // bf16 elems per B row (80B rows: spreads all 8 superbanks)

template <int PHASE>
__global__ __launch_bounds__(512) void k_gemm(const float* __restrict__ Wall,
                                              const float* __restrict__ bias,
                                              const bf16_t* __restrict__ Asrc,
                                              const int* __restrict__ counts,
                                              const int* __restrict__ offs,
                                              const int* __restrict__ slot_tok,
                                              const float* __restrict__ slot_gate,
                                              bf16_t* __restrict__ Hout,
                                              float* __restrict__ out) {
    const int e  = blockIdx.z;
    const int n0 = blockIdx.x * BN;
    const int m0 = blockIdx.y * BM;
    const int cnt = counts[e];
    if (m0 >= cnt) return;
    const int off = offs[e];

    __shared__ bf16_t As[BM * APITCH];   // 16 KB  [m][k]
    __shared__ bf16_t Bs[BN * BPITCH];   // 10 KB  [n][k]

    const int t = threadIdx.x;
    const int lane = t & 63, wv = t >> 6;        // 8 waves
    const int wm = wv & 3, wn = wv >> 2;         // 4 (M) x 2 (N) wave grid
    const int l15 = lane & 15, q = lane >> 4;

    // A staging: wave wv stages rows [wv*32, wv*32+32), 2 global_load_lds(16B)/thread
    const bf16_t* arow[2];
#pragma unroll
    for (int i = 0; i < 2; i++) {
        int rl = wv * 32 + i * 16 + (lane >> 2);
        int slot = off + m0 + rl;
        slot = slot < (NSLOT - 1) ? slot : (NSLOT - 1);   // clamp (dummy rows)
        int srow = (PHASE == 1) ? slot_tok[slot] : slot;
        arow[i] = Asrc + (size_t)srow * DIM + (lane & 3) * 8;
    }
    // B staging: thread t handles col n=t&127, k-octet kh=t>>7
    const int bn = t & 127, kh = t >> 7;
    const float* bsrc = Wall + (size_t)e * DIM * DIM + (size_t)(kh * 8) * DIM + n0 + bn;
    bf16_t* bdst = &Bs[bn * BPITCH + kh * 8];

    f32x4 acc[4][4] = {};

    for (int k0 = 0; k0 < DIM; k0 += BK) {
        __syncthreads();
#pragma unroll
        for (int i = 0; i < 2; i++) {
            bf16_t* ldst = &As[(wv * 32 + i * 16) * APITCH];
            __builtin_amdgcn_global_load_lds(
                (const __attribute__((address_space(1))) uint32_t*)(arow[i] + k0),
                (__attribute__((address_space(3))) uint32_t*)ldst, 16, 0, 0);
        }
        {
            const float* bs = bsrc + (size_t)k0 * DIM;
            float v[8];
#pragma unroll
            for (int kk = 0; kk < 8; kk++) v[kk] = bs[(size_t)kk * DIM];
            bf16x8 pk;
#pragma unroll
            for (int kk = 0; kk < 8; kk++) pk[kk] = (bf16_t)v[kk];
            *reinterpret_cast<bf16x8*>(bdst) = pk;
        }
        __syncthreads();

        bf16x8 af[4], bfr[4];
#pragma unroll
        for (int mf = 0; mf < 4; mf++)
            af[mf] = *reinterpret_cast<const bf16x8*>(&As[(wm * 64 + mf * 16 + l15) * APITCH + q * 8]);
#pragma unroll
        for (int nf = 0; nf < 4; nf++)
            bfr[nf] = *reinterpret_cast<const bf16x8*>(&Bs[(wn * 64 + nf * 16 + l15) * BPITCH + q * 8]);
#pragma unroll
        for (int mf = 0; mf < 4; mf++)
#pragma unroll
            for (int nf = 0; nf < 4; nf++)
                acc[mf][nf] = __builtin_amdgcn_mfma_f32_16x16x32_bf16(af[mf], bfr[nf], acc[mf][nf], 0, 0, 0);
    }

    // epilogue; C/D layout: col = l15, row = q*4 + reg
    const int rows_here = cnt - m0;
#pragma unroll
    for (int mf = 0; mf < 4; mf++) {
#pragma unroll
        for (int r = 0; r < 4; r++) {
            int rl = wm * 64 + mf * 16 + q * 4 + r;
            if (rl >= rows_here) continue;
            int slot = off + m0 + rl;
            if (PHASE == 1) {
#pragma unroll
                for (int nf = 0; nf < 4; nf++) {
                    int col = n0 + wn * 64 + nf * 16 + l15;
                    float h = acc[mf][nf][r] + bias[e * DIM + col];
                    h = fmaxf(h, 0.f);
                    Hout[(size_t)slot * DIM + col] = (bf16_t)h;
                }
            } else {
                float g = slot_gate[slot];
                int tok = slot_tok[slot];
#pragma unroll
                for (int nf = 0; nf < 4; nf++) {
                    int col = n0 + wn * 64 + nf * 16 + l15;
                    float y = acc[mf][nf][r] + bias[e * DIM + col];
                    atomicAdd(&out[(size_t)tok * DIM + col], g * y);
                }
            }
        }
    }
}

// ---------------- launcher ----------------
extern "C" void kernel_launch(void* const* d_in, const int* in_sizes, int n_in,
                              void* d_out, int out_size, void* d_ws, size_t ws_size,
                              hipStream_t stream) {
    const float* x  = (const float*)d_in[0];
    const float* W1 = (const float*)d_in[1];
    const float* b1 = (const float*)d_in[2];
    const float* W2 = (const float*)d_in[3];
    const float* b2 = (const float*)d_in[4];
    const float* Wg = (const float*)d_in[5];
    const float* bg = (const float*)d_in[6];
    float* out = (float*)d_out;
    char*  ws  = (char*)d_ws;

    int*    cursor    = (int*)(ws + WS_CURSOR);
    int*    counts    = (int*)(ws + WS_COUNTS);
    int*    offs      = (int*)(ws + WS_OFFS);
    int*    tok_top   = (int*)(ws + WS_TOK_TOP);
    float*  tok_gate  = (float*)(ws + WS_TOK_GATE);
    int*    slot_tok  = (int*)(ws + WS_SLOT_TOK);
    float*  slot_gate = (float*)(ws + WS_SLOT_GATE);
    float*  imp_part  = (float*)(ws + WS_IMPP);
    bf16_t* xbf       = (bf16_t*)(ws + WS_XBF);
    bf16_t* H         = (bf16_t*)(ws + WS_H);

    hipMemsetAsync(cursor, 0, 1024, stream);                              // padded cursors
    hipMemsetAsync(out, 0, (size_t)NTOK * DIM * sizeof(float), stream);   // out accum

    k_convert_x<<<NTOK * DIM / 1024, 256, 0, stream>>>(x, xbf);
    k_gate<<<NTOK / 4, 256, 0, stream>>>(x, Wg, bg, imp_part, tok_top, tok_gate);
    k_finalize<<<1, 256, 0, stream>>>(imp_part, tok_top, counts, offs, out + (size_t)NTOK * DIM);
    k_scatter<<<NSLOT / 256, 256, 0, stream>>>(tok_top, tok_gate, offs, cursor, slot_tok, slot_gate);

    dim3 grid(DIM / BN, NTOK / BM, NEXP);  // 16 x 8 x 16; dead chunks exit early
    k_gemm<1><<<grid, 512, 0, stream>>>(W1, b1, xbf, counts, offs, slot_tok, slot_gate, H, nullptr);
    k_gemm<2><<<grid, 512, 0, stream>>>(W2, b2, H, counts, offs, slot_tok, slot_gate, nullptr, out);
}